// Round 2
// baseline (3749.198 us; speedup 1.0000x reference)
//
#include <hip/hip_runtime.h>

#define B_ 32
#define N_ 512
#define C_ 1024
#define H_ 16
#define D_ 64
#define TC_ 3072
#define M_ (B_*N_)

typedef unsigned int u32;
typedef unsigned short u16;
typedef __attribute__((ext_vector_type(8))) unsigned short ushort8;

__device__ __forceinline__ float bfl(u32 u){ return __builtin_bit_cast(float, u << 16); }
__device__ __forceinline__ float bfh(u32 u){ return __builtin_bit_cast(float, u & 0xFFFF0000u); }
__device__ __forceinline__ u16 f2bf(float f){
  u32 u = __builtin_bit_cast(u32, f);
  u32 r = (u + 0x7FFFu + ((u >> 16) & 1u)) >> 16;
  return (u16)r;
}
__device__ __forceinline__ void unpack8(uint4 p, float* f){
  f[0]=bfl(p.x); f[1]=bfh(p.x); f[2]=bfl(p.y); f[3]=bfh(p.y);
  f[4]=bfl(p.z); f[5]=bfh(p.z); f[6]=bfl(p.w); f[7]=bfh(p.w);
}

// ---------------- LayerNorm -> x (bf16) ----------------
__global__ __launch_bounds__(256) void k_ln(const float* __restrict__ r,
                                            const float* __restrict__ g,
                                            const float* __restrict__ be,
                                            u16* __restrict__ X) {
  __shared__ float red[8];
  int row = blockIdx.x, t = threadIdx.x;
  float4 v = ((const float4*)(r + (size_t)row * C_))[t];
  float s = (v.x + v.y) + (v.z + v.w);
  #pragma unroll
  for (int o = 32; o; o >>= 1) s += __shfl_xor(s, o);
  if ((t & 63) == 0) red[t >> 6] = s;
  __syncthreads();
  float mean = (red[0] + red[1] + red[2] + red[3]) * (1.f / 1024.f);
  float d0 = v.x - mean, d1 = v.y - mean, d2 = v.z - mean, d3 = v.w - mean;
  float q = d0*d0 + d1*d1 + d2*d2 + d3*d3;
  #pragma unroll
  for (int o = 32; o; o >>= 1) q += __shfl_xor(q, o);
  if ((t & 63) == 0) red[4 + (t >> 6)] = q;
  __syncthreads();
  float var = (red[4] + red[5] + red[6] + red[7]) * (1.f / 1024.f);
  float rs = rsqrtf(var + 1e-5f);
  float4 gv = ((const float4*)g)[t];
  float4 bv = ((const float4*)be)[t];
  ushort4 o4;
  o4.x = f2bf(d0 * rs * gv.x + bv.x);
  o4.y = f2bf(d1 * rs * gv.y + bv.y);
  o4.z = f2bf(d2 * rs * gv.z + bv.z);
  o4.w = f2bf(d3 * rs * gv.w + bv.w);
  ((ushort4*)X)[(size_t)row * 256 + t] = o4;
}

// ---------------- QKV GEMM: x(bf16) @ qkv_w(f32) + b -> QKV bf16 [t][b][h][n][d] ----
#define BM 128
#define BN 128
#define BK 16
__global__ __launch_bounds__(256) void k_qkv(const u16* __restrict__ X,
                                             const float* __restrict__ W,
                                             const float* __restrict__ bias,
                                             u16* __restrict__ QKV) {
  __shared__ float As[BK][BM];
  __shared__ float Bs[BK][BN];
  int t = threadIdx.x;
  int tx = t & 15, ty = t >> 4;
  int rowA0 = blockIdx.x * BM;
  int colB0 = blockIdx.y * BN;
  float acc[8][8] = {};
  for (int k0 = 0; k0 < C_; k0 += BK) {
    { // stage A (transpose to [k][m])
      int r = t >> 1, kc = (t & 1) * 8;
      uint4 pk = *(const uint4*)(X + (size_t)(rowA0 + r) * C_ + k0 + kc);
      float f[8]; unpack8(pk, f);
      #pragma unroll
      for (int i = 0; i < 8; i++) As[kc + i][r] = f[i];
    }
    { // stage B
      int kk = t >> 4, c = (t & 15) * 8;
      const float4* wp = (const float4*)(W + (size_t)(k0 + kk) * TC_ + colB0 + c);
      *(float4*)&Bs[kk][c]     = wp[0];
      *(float4*)&Bs[kk][c + 4] = wp[1];
    }
    __syncthreads();
    #pragma unroll
    for (int kk = 0; kk < BK; kk++) {
      float a[8], b[8];
      *(float4*)&a[0] = *(const float4*)&As[kk][ty * 8];
      *(float4*)&a[4] = *(const float4*)&As[kk][ty * 8 + 4];
      *(float4*)&b[0] = *(const float4*)&Bs[kk][tx * 8];
      *(float4*)&b[4] = *(const float4*)&Bs[kk][tx * 8 + 4];
      #pragma unroll
      for (int i = 0; i < 8; i++)
        #pragma unroll
        for (int j = 0; j < 8; j++)
          acc[i][j] = fmaf(a[i], b[j], acc[i][j]);
    }
    __syncthreads();
  }
  // epilogue: +bias, scatter to [t][b][h][n][d] bf16
  int j0 = colB0 + tx * 8;
  int tsel = j0 >> 10;
  int rem = j0 & 1023;
  int h = rem >> 6, dd = rem & 63;
  float bv[8];
  #pragma unroll
  for (int j = 0; j < 8; j++) bv[j] = bias[j0 + j];
  #pragma unroll
  for (int i = 0; i < 8; i++) {
    int mg = rowA0 + ty * 8 + i;
    int b = mg >> 9, n = mg & 511;
    size_t dst = ((((size_t)tsel * B_ + b) * H_ + h) * N_ + n) * D_ + dd;
    ushort8 o;
    #pragma unroll
    for (int j = 0; j < 8; j++) o[j] = f2bf(acc[i][j] + bv[j]);
    *(ushort8*)(QKV + dst) = o;
  }
}

// ---------------- attention: per (b,h) softmax column-weights -> outbar ----------
__global__ __launch_bounds__(256) void k_attn(const u16* __restrict__ QKV,
                                              float* __restrict__ outbar) {
  extern __shared__ __align__(16) unsigned char smem[];   // 64 KiB dynamic
  u16* ks = (u16*)smem;                                   // [512][64] swizzled
  int bh = blockIdx.x;
  const u16* qb = QKV + (size_t)bh * (N_ * D_);
  const u16* kb = QKV + (size_t)(B_ * H_ + bh) * (N_ * D_);
  const u16* vb = QKV + (size_t)(2 * B_ * H_ + bh) * (N_ * D_);
  int t = threadIdx.x, lane = t & 63, w = t >> 6;

  // stage K, XOR-swizzled 16B slots: slot = d8 ^ (c&7)
  #pragma unroll
  for (int i = 0; i < 16; i++) {
    int vec = t + i * 256;
    int c = vec >> 3, d8 = vec & 7;
    uint4 pk = *(const uint4*)(kb + ((size_t)c << 6) + (d8 << 3));
    *(uint4*)(ks + (c << 6) + (((u32)d8 ^ (c & 7)) << 3)) = pk;
  }
  __syncthreads();

  float colw[8] = {0.f,0.f,0.f,0.f,0.f,0.f,0.f,0.f};

  for (int n = w * 128; n < w * 128 + 128; n++) {
    float qf[64];
    #pragma unroll
    for (int g = 0; g < 8; g++) {
      uint4 pk = *(const uint4*)(qb + ((size_t)n << 6) + (g << 3));
      unpack8(pk, &qf[g * 8]);
    }
    float lg[8];
    #pragma unroll
    for (int j = 0; j < 8; j++) {
      int c = lane + (j << 6);
      int sw_ = (c & 7) << 3;
      float acc = 0.f;
      #pragma unroll
      for (int g = 0; g < 8; g++) {
        uint4 pk = *(const uint4*)(ks + (c << 6) + ((g << 3) ^ sw_));
        float kf[8]; unpack8(pk, kf);
        #pragma unroll
        for (int e = 0; e < 8; e++) acc = fmaf(qf[g * 8 + e], kf[e], acc);
      }
      lg[j] = acc * 0.125f;
    }
    float m = lg[0];
    #pragma unroll
    for (int j = 1; j < 8; j++) m = fmaxf(m, lg[j]);
    #pragma unroll
    for (int o = 32; o; o >>= 1) m = fmaxf(m, __shfl_xor(m, o));
    float e[8], s = 0.f;
    #pragma unroll
    for (int j = 0; j < 8; j++) { e[j] = __expf(lg[j] - m); s += e[j]; }
    #pragma unroll
    for (int o = 32; o; o >>= 1) s += __shfl_xor(s, o);
    float rs = 1.0f / s;
    #pragma unroll
    for (int j = 0; j < 8; j++) colw[j] += e[j] * rs;
  }
  __syncthreads();            // everyone done reading ks -> reuse LDS
  float* colws = (float*)smem;  // [4][512] then psum[256] at +2048
  #pragma unroll
  for (int j = 0; j < 8; j++) colws[w * 512 + lane + (j << 6)] = colw[j];
  __syncthreads();
  for (int c = t; c < 512; c += 256) {
    float tot = colws[c] + colws[512 + c] + colws[1024 + c] + colws[1536 + c];
    colws[c] = tot * (1.f / 512.f);
  }
  __syncthreads();
  int dd = t & 63, mc = t >> 6;
  float acc = 0.f;
  for (int m2 = mc * 128; m2 < mc * 128 + 128; m2++) {
    float vv = bfl((u32)vb[((size_t)m2 << 6) + dd]);
    acc = fmaf(colws[m2], vv, acc);
  }
  colws[2048 + t] = acc;
  __syncthreads();
  if (t < 64) {
    float o = colws[2048 + t] + colws[2048 + 64 + t] + colws[2048 + 128 + t] + colws[2048 + 192 + t];
    outbar[(size_t)bh * 64 + t] = o;
  }
}

// ---------------- abar + mu = 2*(abar@proj_w + proj_b) ----------------
__global__ __launch_bounds__(256) void k_head1(const float* __restrict__ outbar,
                                               const float* __restrict__ pw,
                                               const float* __restrict__ pb,
                                               float* __restrict__ mu) {
  __shared__ float abar[1024];
  int t = threadIdx.x;
  for (int j = t; j < 1024; j += 256) {
    float s = 0.f;
    #pragma unroll 4
    for (int b = 0; b < 32; b++) s += outbar[b * 1024 + j];
    abar[j] = s * (1.f / 32.f);
  }
  __syncthreads();
  int c = blockIdx.x * 256 + t;
  float acc = pb[c];
  for (int j = 0; j < 1024; j++) acc = fmaf(abar[j], pw[(size_t)j * 1024 + c], acc);
  mu[c] = 2.f * acc;
}

// ---------------- sigma = 0.1 + 0.9*sigmoid(mu@sig_w + sig_b) ----------------
__global__ __launch_bounds__(256) void k_head2(const float* __restrict__ mu,
                                               const float* __restrict__ sw,
                                               const float* __restrict__ sb,
                                               float* __restrict__ sig) {
  __shared__ float ms[1024];
  int t = threadIdx.x;
  for (int j = t; j < 1024; j += 256) ms[j] = mu[j];
  __syncthreads();
  int c = blockIdx.x * 256 + t;
  float acc = sb[c];
  for (int j = 0; j < 1024; j++) acc = fmaf(ms[j], sw[(size_t)j * 1024 + c], acc);
  float s = 1.f / (1.f + expf(-acc));
  sig[c] = 0.1f + 0.9f * s;
}

// ---------------- eps (JAX threefry, partitionable) + latent ----------------
__device__ __forceinline__ uint2 threefry_0_42(u32 x0, u32 x1) {
  const u32 ks0 = 0u, ks1 = 42u, ks2 = 0x1BD11BF0u; // 0 ^ 42 ^ 0x1BD11BDA
  x0 += ks0; x1 += ks1;
  #define RND(r) { x0 += x1; x1 = (x1 << r) | (x1 >> (32 - r)); x1 ^= x0; }
  RND(13) RND(15) RND(26) RND(6)   x0 += ks1; x1 += ks2 + 1u;
  RND(17) RND(29) RND(16) RND(24)  x0 += ks2; x1 += ks0 + 2u;
  RND(13) RND(15) RND(26) RND(6)   x0 += ks0; x1 += ks1 + 3u;
  RND(17) RND(29) RND(16) RND(24)  x0 += ks1; x1 += ks2 + 4u;
  RND(13) RND(15) RND(26) RND(6)   x0 += ks2; x1 += ks0 + 5u;
  #undef RND
  return make_uint2(x0, x1);
}

__device__ __forceinline__ float bits_to_normal(u32 bits) {
  u32 fb = (bits >> 9) | 0x3F800000u;
  float fl = __builtin_bit_cast(float, fb) - 1.0f;          // [0,1)
  float u = __fmul_rn(fl, 2.0f);                            // (maxval-minval) rounds to 2.0f
  u = __fadd_rn(u, -0.99999994f);
  u = fmaxf(-0.99999994f, u);
  float x = u;
  float wv = -log1pf(-x * x);
  float p;
  if (wv < 5.0f) {
    wv -= 2.5f;
    p = 2.81022636e-08f;
    p = fmaf(p, wv, 3.43273939e-07f);
    p = fmaf(p, wv, -3.5233877e-06f);
    p = fmaf(p, wv, -4.39150654e-06f);
    p = fmaf(p, wv, 0.00021858087f);
    p = fmaf(p, wv, -0.00125372503f);
    p = fmaf(p, wv, -0.00417768164f);
    p = fmaf(p, wv, 0.246640727f);
    p = fmaf(p, wv, 1.50140941f);
  } else {
    wv = sqrtf(wv) - 3.0f;
    p = -0.000200214257f;
    p = fmaf(p, wv, 0.000100950558f);
    p = fmaf(p, wv, 0.00134934322f);
    p = fmaf(p, wv, -0.00367342844f);
    p = fmaf(p, wv, 0.00573950773f);
    p = fmaf(p, wv, -0.0076224613f);
    p = fmaf(p, wv, 0.00943887047f);
    p = fmaf(p, wv, 1.00167406f);
    p = fmaf(p, wv, 2.83297682f);
  }
  return 1.41421356f * (p * x);
}

__global__ __launch_bounds__(256) void k_latent(const float* __restrict__ mu,
                                                const float* __restrict__ sig,
                                                float* __restrict__ out) {
  u32 f = blockIdx.x * 256 + threadIdx.x;   // 0..65535 element index
  uint2 rb = threefry_0_42(0u, f);          // counter = (hi,lo) of 64-bit index
  float eps = bits_to_normal(rb.x ^ rb.y);  // partitionable 32-bit: XOR of both words
  int c = f & 1023;
  out[f] = mu[c] + sig[c] * eps;
}

extern "C" void kernel_launch(void* const* d_in, const int* in_sizes, int n_in,
                              void* d_out, int out_size, void* d_ws, size_t ws_size,
                              hipStream_t stream) {
  const float* r    = (const float*)d_in[0];
  const float* lng  = (const float*)d_in[1];
  const float* lnb  = (const float*)d_in[2];
  const float* qkvw = (const float*)d_in[3];
  const float* qkvb = (const float*)d_in[4];
  const float* pw   = (const float*)d_in[5];
  const float* pb   = (const float*)d_in[6];
  const float* sw   = (const float*)d_in[7];
  const float* sb   = (const float*)d_in[8];
  float* out = (float*)d_out;

  u16* X   = (u16*)d_ws;                         // 16384*1024 bf16   (32 MiB)
  u16* QKV = X + (size_t)M_ * C_;                // 3*16384*1024 bf16 (96 MiB)
  float* OUTBAR = (float*)(QKV + (size_t)3 * M_ * C_); // 32*16*64 f32
  float* MU  = OUTBAR + B_ * C_;                 // 1024
  float* SIG = MU + C_;                          // 1024

  k_ln<<<M_, 256, 0, stream>>>(r, lng, lnb, X);
  dim3 gq(M_ / BM, TC_ / BN);
  k_qkv<<<gq, 256, 0, stream>>>(X, qkvw, qkvb, QKV);
  k_attn<<<B_ * H_, 256, 65536, stream>>>(QKV, OUTBAR);
  k_head1<<<4, 256, 0, stream>>>(OUTBAR, pw, pb, MU);
  k_head2<<<4, 256, 0, stream>>>(MU, sw, sb, SIG);
  k_latent<<<256, 256, 0, stream>>>(MU, SIG, out);
}

// Round 3
// 335.352 us; speedup vs baseline: 11.1799x; 11.1799x over previous
//
#include <hip/hip_runtime.h>

#define B_ 32
#define N_ 512
#define C_ 1024
#define H_ 16
#define D_ 64
#define TC_ 3072
#define M_ (B_*N_)

typedef unsigned int u32;
typedef unsigned short u16;
typedef __attribute__((ext_vector_type(8))) unsigned short ushort8;
typedef __attribute__((ext_vector_type(8))) short bf16x8;   // 8 bf16 (4 VGPRs)
typedef __attribute__((ext_vector_type(4))) float f32x4;

__device__ __forceinline__ float bfl(u32 u){ return __builtin_bit_cast(float, u << 16); }
__device__ __forceinline__ u16 f2bf(float f){
  u32 u = __builtin_bit_cast(u32, f);
  u32 r = (u + 0x7FFFu + ((u >> 16) & 1u)) >> 16;
  return (u16)r;
}

// ---------------- LayerNorm -> x (bf16) ----------------
__global__ __launch_bounds__(256) void k_ln(const float* __restrict__ r,
                                            const float* __restrict__ g,
                                            const float* __restrict__ be,
                                            u16* __restrict__ X) {
  __shared__ float red[8];
  int row = blockIdx.x, t = threadIdx.x;
  float4 v = ((const float4*)(r + (size_t)row * C_))[t];
  float s = (v.x + v.y) + (v.z + v.w);
  #pragma unroll
  for (int o = 32; o; o >>= 1) s += __shfl_xor(s, o);
  if ((t & 63) == 0) red[t >> 6] = s;
  __syncthreads();
  float mean = (red[0] + red[1] + red[2] + red[3]) * (1.f / 1024.f);
  float d0 = v.x - mean, d1 = v.y - mean, d2 = v.z - mean, d3 = v.w - mean;
  float q = d0*d0 + d1*d1 + d2*d2 + d3*d3;
  #pragma unroll
  for (int o = 32; o; o >>= 1) q += __shfl_xor(q, o);
  if ((t & 63) == 0) red[4 + (t >> 6)] = q;
  __syncthreads();
  float var = (red[4] + red[5] + red[6] + red[7]) * (1.f / 1024.f);
  float rs = rsqrtf(var + 1e-5f);
  float4 gv = ((const float4*)g)[t];
  float4 bv = ((const float4*)be)[t];
  ushort4 o4;
  o4.x = f2bf(d0 * rs * gv.x + bv.x);
  o4.y = f2bf(d1 * rs * gv.y + bv.y);
  o4.z = f2bf(d2 * rs * gv.z + bv.z);
  o4.w = f2bf(d3 * rs * gv.w + bv.w);
  ((ushort4*)X)[(size_t)row * 256 + t] = o4;
}

// ---------------- W (f32 [k][n]) -> WT (bf16 [n][k]) ----------------
__global__ __launch_bounds__(256) void k_wcvt(const float* __restrict__ W,
                                              u16* __restrict__ WT) {
  __shared__ float tile[32][33];
  int k0 = blockIdx.x * 32, n0 = blockIdx.y * 32;
  int t = threadIdx.x;
  int r = t >> 3, c4 = (t & 7) * 4;
  float4 v = *(const float4*)(W + (size_t)(k0 + r) * TC_ + n0 + c4);
  tile[r][c4] = v.x; tile[r][c4 + 1] = v.y; tile[r][c4 + 2] = v.z; tile[r][c4 + 3] = v.w;
  __syncthreads();
  int n = t >> 3, k4 = (t & 7) * 4;
  ushort4 o;
  o.x = f2bf(tile[k4][n]);     o.y = f2bf(tile[k4 + 1][n]);
  o.z = f2bf(tile[k4 + 2][n]); o.w = f2bf(tile[k4 + 3][n]);
  *(ushort4*)(WT + (size_t)(n0 + n) * C_ + k0 + k4) = o;
}

// ---------------- QKV GEMM (MFMA bf16): X[m][k] @ WT[n][k]^T -> QKV bf16 ----
__global__ __launch_bounds__(256) void k_qkv(const u16* __restrict__ X,
                                             const u16* __restrict__ WT,
                                             const float* __restrict__ bias,
                                             u16* __restrict__ QKV) {
  __shared__ u16 As[128 * 32];   // [row][32k] rows 64B, 16B slots swizzled by row&3
  __shared__ u16 Bs[128 * 32];
  int t = threadIdx.x, lane = t & 63, w = t >> 6;
  int wr = w >> 1, wc = w & 1;
  int rowA0 = blockIdx.x * 128, colB0 = blockIdx.y * 128;
  int colbase = lane & 15, kslot = lane >> 4;

  f32x4 acc[4][4] = {};

  for (int k0 = 0; k0 < C_; k0 += 32) {
    __syncthreads();
    const u16* Xrow = X + (size_t)rowA0 * C_ + k0;
    const u16* Wrow = WT + (size_t)colB0 * C_ + k0;
    #pragma unroll
    for (int p = 0; p < 2; p++) {
      int o = p * 4096 + w * 1024 + lane * 16;  // byte offset in As
      int row = o >> 6, slot = (o >> 4) & 3;
      int kb16 = slot ^ (row & 3);              // pre-swizzled global source
      const u16* gp = Xrow + (size_t)row * C_ + (kb16 << 3);
      __builtin_amdgcn_global_load_lds((const __attribute__((address_space(1))) void*)gp,
                                       (__attribute__((address_space(3))) void*)((char*)As + o),
                                       16, 0, 0);
    }
    #pragma unroll
    for (int p = 0; p < 2; p++) {
      int o = p * 4096 + w * 1024 + lane * 16;
      int row = o >> 6, slot = (o >> 4) & 3;
      int kb16 = slot ^ (row & 3);
      const u16* gp = Wrow + (size_t)row * C_ + (kb16 << 3);
      __builtin_amdgcn_global_load_lds((const __attribute__((address_space(1))) void*)gp,
                                       (__attribute__((address_space(3))) void*)((char*)Bs + o),
                                       16, 0, 0);
    }
    __syncthreads();
    bf16x8 a[4], b[4];
    #pragma unroll
    for (int i = 0; i < 4; i++) {
      int row = wr * 64 + i * 16 + colbase;
      a[i] = *(const bf16x8*)((const char*)As + row * 64 + ((kslot ^ (row & 3)) << 4));
    }
    #pragma unroll
    for (int j = 0; j < 4; j++) {
      int col = wc * 64 + j * 16 + colbase;
      b[j] = *(const bf16x8*)((const char*)Bs + col * 64 + ((kslot ^ (col & 3)) << 4));
    }
    #pragma unroll
    for (int i = 0; i < 4; i++)
      #pragma unroll
      for (int j = 0; j < 4; j++)
        acc[i][j] = __builtin_amdgcn_mfma_f32_16x16x32_bf16(a[i], b[j], acc[i][j], 0, 0, 0);
  }

  // epilogue: +bias, f2bf, scatter to [t][b][h][n][d]
  float bv[4];
  #pragma unroll
  for (int j = 0; j < 4; j++) bv[j] = bias[colB0 + wc * 64 + j * 16 + colbase];
  #pragma unroll
  for (int i = 0; i < 4; i++) {
    #pragma unroll
    for (int j = 0; j < 4; j++) {
      int col = colB0 + wc * 64 + j * 16 + colbase;
      int tsel = col >> 10, rem = col & 1023;
      int h = rem >> 6, dd = rem & 63;
      #pragma unroll
      for (int q = 0; q < 4; q++) {
        int m = rowA0 + wr * 64 + i * 16 + (lane >> 4) * 4 + q;
        int b2 = m >> 9, n = m & 511;
        QKV[(((size_t)(tsel * B_ + b2) * H_ + h) * N_ + n) * D_ + dd] = f2bf(acc[i][j][q] + bv[j]);
      }
    }
  }
}

// ---------------- attention (MFMA): softmax column-weights -> outbar ----------
__global__ __launch_bounds__(256) void k_attn(const u16* __restrict__ QKV,
                                              float* __restrict__ outbar) {
  __shared__ u16 Ks[N_ * D_];   // 64KB, rows 128B, 16B slots swizzled by row&7
  int bh = blockIdx.x;
  const u16* qb = QKV + (size_t)bh * (N_ * D_);
  const u16* kb = QKV + (size_t)(B_ * H_ + bh) * (N_ * D_);
  const u16* vb = QKV + (size_t)(2 * B_ * H_ + bh) * (N_ * D_);
  int t = threadIdx.x, lane = t & 63, w = t >> 6;
  int colbase = lane & 15, kslot = lane >> 4;

  #pragma unroll
  for (int i2 = 0; i2 < 16; i2++) {
    int vec = t + i2 * 256;                 // 0..4095 16B-granules
    int c = vec >> 3, d8 = vec & 7;
    uint4 pk = *(const uint4*)(kb + ((size_t)c << 6) + (d8 << 3));
    *(uint4*)((char*)Ks + c * 128 + ((d8 ^ (c & 7)) << 4)) = pk;
  }
  __syncthreads();

  float cwreg[32];
  #pragma unroll
  for (int tl = 0; tl < 32; tl++) cwreg[tl] = 0.f;

  for (int si = 0; si < 8; si++) {
    int n0 = (w * 8 + si) * 16;
    bf16x8 aq0 = *(const bf16x8*)(qb + (size_t)(n0 + colbase) * 64 + kslot * 8);
    bf16x8 aq1 = *(const bf16x8*)(qb + (size_t)(n0 + colbase) * 64 + 32 + kslot * 8);
    f32x4 acc[32];
    #pragma unroll
    for (int tl = 0; tl < 32; tl++) {
      int m = tl * 16 + colbase;
      const char* kr = (const char*)Ks + m * 128;
      bf16x8 bk0 = *(const bf16x8*)(kr + ((kslot ^ (m & 7)) << 4));
      bf16x8 bk1 = *(const bf16x8*)(kr + (((kslot + 4) ^ (m & 7)) << 4));
      f32x4 z = {0.f, 0.f, 0.f, 0.f};
      z = __builtin_amdgcn_mfma_f32_16x16x32_bf16(aq0, bk0, z, 0, 0, 0);
      acc[tl] = __builtin_amdgcn_mfma_f32_16x16x32_bf16(aq1, bk1, z, 0, 0, 0);
    }
    float mj[4] = {-1e30f, -1e30f, -1e30f, -1e30f};
    #pragma unroll
    for (int tl = 0; tl < 32; tl++)
      #pragma unroll
      for (int q = 0; q < 4; q++) mj[q] = fmaxf(mj[q], acc[tl][q]);
    #pragma unroll
    for (int q = 0; q < 4; q++) {
      mj[q] = fmaxf(mj[q], __shfl_xor(mj[q], 1));
      mj[q] = fmaxf(mj[q], __shfl_xor(mj[q], 2));
      mj[q] = fmaxf(mj[q], __shfl_xor(mj[q], 4));
      mj[q] = fmaxf(mj[q], __shfl_xor(mj[q], 8));
    }
    float sj[4] = {0.f, 0.f, 0.f, 0.f};
    #pragma unroll
    for (int tl = 0; tl < 32; tl++)
      #pragma unroll
      for (int q = 0; q < 4; q++) {
        float e = __expf((acc[tl][q] - mj[q]) * 0.125f);
        acc[tl][q] = e;
        sj[q] += e;
      }
    #pragma unroll
    for (int q = 0; q < 4; q++) {
      sj[q] += __shfl_xor(sj[q], 1);
      sj[q] += __shfl_xor(sj[q], 2);
      sj[q] += __shfl_xor(sj[q], 4);
      sj[q] += __shfl_xor(sj[q], 8);
    }
    float rs0 = 1.f / sj[0], rs1 = 1.f / sj[1], rs2 = 1.f / sj[2], rs3 = 1.f / sj[3];
    #pragma unroll
    for (int tl = 0; tl < 32; tl++)
      cwreg[tl] += acc[tl][0] * rs0 + acc[tl][1] * rs1 + acc[tl][2] * rs2 + acc[tl][3] * rs3;
  }
  #pragma unroll
  for (int tl = 0; tl < 32; tl++) {
    cwreg[tl] += __shfl_xor(cwreg[tl], 16);
    cwreg[tl] += __shfl_xor(cwreg[tl], 32);
  }
  __syncthreads();              // done reading Ks -> overlay
  float* cw = (float*)Ks;       // [4][512] partials + psum[256] at +2048
  #pragma unroll
  for (int r = 0; r < 8; r++) {
    int tl = (lane >> 4) + r * 4;
    cw[w * 512 + tl * 16 + colbase] = cwreg[tl];
  }
  __syncthreads();
  for (int c = t; c < 512; c += 256) {
    float tot = cw[c] + cw[512 + c] + cw[1024 + c] + cw[1536 + c];
    cw[c] = tot * (1.f / 512.f);
  }
  __syncthreads();
  int dd = t & 63, mc = t >> 6;
  float acc2 = 0.f;
  for (int m2 = mc * 128; m2 < mc * 128 + 128; m2++)
    acc2 = fmaf(cw[m2], bfl((u32)vb[((size_t)m2 << 6) + dd]), acc2);
  cw[2048 + t] = acc2;
  __syncthreads();
  if (t < 64)
    outbar[(size_t)bh * 64 + t] =
        cw[2048 + t] + cw[2048 + 64 + t] + cw[2048 + 128 + t] + cw[2048 + 192 + t];
}

// ---------------- abar + mu = 2*(abar@proj_w + proj_b) ----------------
__global__ __launch_bounds__(256) void k_head1(const float* __restrict__ outbar,
                                               const float* __restrict__ pw,
                                               const float* __restrict__ pb,
                                               float* __restrict__ mu) {
  __shared__ float abar[1024];
  int t = threadIdx.x;
  for (int j = t; j < 1024; j += 256) {
    float s = 0.f;
    #pragma unroll 4
    for (int b = 0; b < 32; b++) s += outbar[b * 1024 + j];
    abar[j] = s * (1.f / 32.f);
  }
  __syncthreads();
  int c = blockIdx.x * 256 + t;
  float acc = pb[c];
  for (int j = 0; j < 1024; j++) acc = fmaf(abar[j], pw[(size_t)j * 1024 + c], acc);
  mu[c] = 2.f * acc;
}

// ---------------- sigma = 0.1 + 0.9*sigmoid(mu@sig_w + sig_b) ----------------
__global__ __launch_bounds__(256) void k_head2(const float* __restrict__ mu,
                                               const float* __restrict__ sw,
                                               const float* __restrict__ sb,
                                               float* __restrict__ sig) {
  __shared__ float ms[1024];
  int t = threadIdx.x;
  for (int j = t; j < 1024; j += 256) ms[j] = mu[j];
  __syncthreads();
  int c = blockIdx.x * 256 + t;
  float acc = sb[c];
  for (int j = 0; j < 1024; j++) acc = fmaf(ms[j], sw[(size_t)j * 1024 + c], acc);
  float s = 1.f / (1.f + expf(-acc));
  sig[c] = 0.1f + 0.9f * s;
}

// ---------------- eps (JAX threefry, partitionable) + latent ----------------
__device__ __forceinline__ uint2 threefry_0_42(u32 x0, u32 x1) {
  const u32 ks0 = 0u, ks1 = 42u, ks2 = 0x1BD11BF0u;
  x0 += ks0; x1 += ks1;
  #define RND(r) { x0 += x1; x1 = (x1 << r) | (x1 >> (32 - r)); x1 ^= x0; }
  RND(13) RND(15) RND(26) RND(6)   x0 += ks1; x1 += ks2 + 1u;
  RND(17) RND(29) RND(16) RND(24)  x0 += ks2; x1 += ks0 + 2u;
  RND(13) RND(15) RND(26) RND(6)   x0 += ks0; x1 += ks1 + 3u;
  RND(17) RND(29) RND(16) RND(24)  x0 += ks1; x1 += ks2 + 4u;
  RND(13) RND(15) RND(26) RND(6)   x0 += ks2; x1 += ks0 + 5u;
  #undef RND
  return make_uint2(x0, x1);
}

__device__ __forceinline__ float bits_to_normal(u32 bits) {
  u32 fb = (bits >> 9) | 0x3F800000u;
  float fl = __builtin_bit_cast(float, fb) - 1.0f;
  float u = __fmul_rn(fl, 2.0f);
  u = __fadd_rn(u, -0.99999994f);
  u = fmaxf(-0.99999994f, u);
  float x = u;
  float wv = -log1pf(-x * x);
  float p;
  if (wv < 5.0f) {
    wv -= 2.5f;
    p = 2.81022636e-08f;
    p = fmaf(p, wv, 3.43273939e-07f);
    p = fmaf(p, wv, -3.5233877e-06f);
    p = fmaf(p, wv, -4.39150654e-06f);
    p = fmaf(p, wv, 0.00021858087f);
    p = fmaf(p, wv, -0.00125372503f);
    p = fmaf(p, wv, -0.00417768164f);
    p = fmaf(p, wv, 0.246640727f);
    p = fmaf(p, wv, 1.50140941f);
  } else {
    wv = sqrtf(wv) - 3.0f;
    p = -0.000200214257f;
    p = fmaf(p, wv, 0.000100950558f);
    p = fmaf(p, wv, 0.00134934322f);
    p = fmaf(p, wv, -0.00367342844f);
    p = fmaf(p, wv, 0.00573950773f);
    p = fmaf(p, wv, -0.0076224613f);
    p = fmaf(p, wv, 0.00943887047f);
    p = fmaf(p, wv, 1.00167406f);
    p = fmaf(p, wv, 2.83297682f);
  }
  return 1.41421356f * (p * x);
}

__global__ __launch_bounds__(256) void k_latent(const float* __restrict__ mu,
                                                const float* __restrict__ sig,
                                                float* __restrict__ out) {
  u32 f = blockIdx.x * 256 + threadIdx.x;
  uint2 rb = threefry_0_42(0u, f);
  float eps = bits_to_normal(rb.x ^ rb.y);
  int c = f & 1023;
  out[f] = mu[c] + sig[c] * eps;
}

extern "C" void kernel_launch(void* const* d_in, const int* in_sizes, int n_in,
                              void* d_out, int out_size, void* d_ws, size_t ws_size,
                              hipStream_t stream) {
  const float* r    = (const float*)d_in[0];
  const float* lng  = (const float*)d_in[1];
  const float* lnb  = (const float*)d_in[2];
  const float* qkvw = (const float*)d_in[3];
  const float* qkvb = (const float*)d_in[4];
  const float* pw   = (const float*)d_in[5];
  const float* pb   = (const float*)d_in[6];
  const float* sw   = (const float*)d_in[7];
  const float* sb   = (const float*)d_in[8];
  float* out = (float*)d_out;

  u16* X   = (u16*)d_ws;                           // 32 MiB
  u16* QKV = X + (size_t)M_ * C_;                  // 96 MiB
  u16* WT  = QKV + (size_t)3 * M_ * C_;            // 6 MiB (bf16 [3072][1024])
  float* OUTBAR = (float*)(WT + (size_t)TC_ * C_); // 32*16*64 f32
  float* MU  = OUTBAR + B_ * C_;
  float* SIG = MU + C_;

  k_ln<<<M_, 256, 0, stream>>>(r, lng, lnb, X);
  k_wcvt<<<dim3(C_ / 32, TC_ / 32), 256, 0, stream>>>(qkvw, WT);
  k_qkv<<<dim3(M_ / 128, TC_ / 128), 256, 0, stream>>>(X, WT, qkvb, QKV);
  k_attn<<<B_ * H_, 256, 0, stream>>>(QKV, OUTBAR);
  k_head1<<<4, 256, 0, stream>>>(OUTBAR, pw, pb, MU);
  k_head2<<<4, 256, 0, stream>>>(MU, sw, sb, SIG);
  k_latent<<<256, 256, 0, stream>>>(MU, SIG, out);
}